// Round 1
// baseline (192.610 us; speedup 1.0000x reference)
//
#include <hip/hip_runtime.h>
#include <cstdint>

// ---------------------------------------------------------------------------
// ObjectBoxDetect: 3-level YOLO head decode, fp32.
//   L0: x[16,256,80,80],  W[85,256],  stride 8,  anchors 0..6399
//   L1: x[16,512,40,40],  W[85,512],  stride 16, anchors 6400..7999
//   L2: x[16,1024,20,20], W[85,1024], stride 32, anchors 8000..8399
// out[16, 8400, 85] fp32.
// ---------------------------------------------------------------------------

// ws layout (floats), padded between regions
constexpr int WT0_OFF = 0;               // 256*85  = 21760
constexpr int WT1_OFF = 21760 + 64;      // 512*85  = 43520
constexpr int WT2_OFF = WT1_OFF + 43520 + 64;  // 1024*85 = 87040
constexpr int WS_NEED_FLOATS = WT2_OFF + 87040 + 64;

// One-shot transpose W[o][c] -> Wt[c][o] for all three levels.
__global__ __launch_bounds__(256) void prep_wt_all(
    const float* __restrict__ W0, const float* __restrict__ W1,
    const float* __restrict__ W2, float* __restrict__ ws)
{
    int i = blockIdx.x * 256 + threadIdx.x;
    if (i < 21760) {
        int c = i / 85, o = i - 85 * c;
        ws[WT0_OFF + i] = W0[o * 256 + c];
    } else if (i < 21760 + 43520) {
        int k = i - 21760;
        int c = k / 85, o = k - 85 * c;
        ws[WT1_OFF + k] = W1[o * 512 + c];
    } else if (i < 21760 + 43520 + 87040) {
        int k = i - (21760 + 43520);
        int c = k / 85, o = k - 85 * c;
        ws[WT2_OFF + k] = W2[o * 1024 + c];
    }
}

// Decode ONUM outputs [o_lo, o_lo+ONUM) for one spatial position.
// pos = b*HW + hw. W uniform across the wave -> scalar loads.
template <int C, int HW, int NXY, int LEVEL, int ONUM, bool BOX, bool TR>
__device__ __forceinline__ void decode_path(
    const float* __restrict__ feat, const float* __restrict__ Wm,
    const float* __restrict__ bias, float* __restrict__ out,
    int o_lo, int pos)
{
    const int b  = pos / HW;
    const int hw = pos - b * HW;
    const float* fp = feat + (size_t)b * (C * HW) + hw;

    float acc[ONUM];
#pragma unroll
    for (int j = 0; j < ONUM; ++j) acc[j] = bias[o_lo + j];

#pragma unroll 4
    for (int c = 0; c < C; ++c) {
        float fv = fp[(size_t)c * HW];
        if constexpr (TR) {
            const float* wr = Wm + c * 85 + o_lo;
#pragma unroll
            for (int j = 0; j < ONUM; ++j)
                acc[j] = fmaf(fv, wr[j], acc[j]);
        } else {
#pragma unroll
            for (int j = 0; j < ONUM; ++j)
                acc[j] = fmaf(fv, Wm[(o_lo + j) * C + c], acc[j]);
        }
    }

    // sigmoid
#pragma unroll
    for (int j = 0; j < ONUM; ++j) {
        float e = __expf(-acc[j]);
        acc[j] = __builtin_amdgcn_rcpf(1.0f + e);
    }

    constexpr float STRIDE = (float)(8 << LEVEL);
    constexpr int AOFF = (LEVEL == 0) ? 0 : ((LEVEL == 1) ? 6400 : 8000);
    float* op = out + ((size_t)b * 8400 + AOFF + hw) * 85 + o_lo;

    if constexpr (BOX) {
        constexpr float P4 = 4.0f * (float)(1 << LEVEL);  // (2y)^2 * 2^l = 4 y^2 2^l
        float wx = (float)(hw % NXY);
        float wy = (float)(hw / NXY);
        float d0 = acc[0] * acc[0] * P4;
        float d1 = acc[1] * acc[1] * P4;
        float d2 = acc[2] * acc[2] * P4;
        float d3 = acc[3] * acc[3] * P4;
        float x1 = (wx + 1.0f - d0) * STRIDE;
        float y1 = (wy + 1.0f - d1) * STRIDE;
        float x2 = (wx + d2) * STRIDE;
        float y2 = (wy + d3) * STRIDE;
        op[0] = (x1 + x2) * 0.5f;
        op[1] = (y1 + y2) * 0.5f;
        op[2] = x2 - x1;
        op[3] = y2 - y1;
#pragma unroll
        for (int j = 4; j < ONUM; ++j) op[j] = acc[j];
    } else {
#pragma unroll
        for (int j = 0; j < ONUM; ++j) op[j] = acc[j];
    }
}

// Fused kernel. 700 blocks x 256 threads (4 waves). Per-wave work equalized:
//   blk [0,400):   L0, 256 pos/block, each wave 64 pos x 85 outs (256*85 FMA/thr)
//   blk [400,600): L1, 128 pos/block, wave pairs split outs {43,42} (512*43)
//   blk [600,700): L2,  64 pos/block, 4 waves split outs {22,22,22,19} (1024*22)
template <bool TR>
__global__ __launch_bounds__(256) void detect_kernel(
    const float* __restrict__ x0, const float* __restrict__ x1,
    const float* __restrict__ x2,
    const float* __restrict__ w0, const float* __restrict__ w1,
    const float* __restrict__ w2,
    const float* __restrict__ b0, const float* __restrict__ b1,
    const float* __restrict__ b2,
    float* __restrict__ out)
{
    const int blk  = blockIdx.x;
    const int wave = threadIdx.x >> 6;
    const int lane = threadIdx.x & 63;

    if (blk < 400) {
        int pos = blk * 256 + wave * 64 + lane;
        decode_path<256, 6400, 80, 0, 85, true, TR>(x0, w0, b0, out, 0, pos);
    } else if (blk < 600) {
        int bb  = blk - 400;
        int grp = wave >> 1;
        int pos = bb * 128 + grp * 64 + lane;
        if ((wave & 1) == 0)
            decode_path<512, 1600, 40, 1, 43, true,  TR>(x1, w1, b1, out, 0,  pos);
        else
            decode_path<512, 1600, 40, 1, 42, false, TR>(x1, w1, b1, out, 43, pos);
    } else {
        int bb  = blk - 600;
        int pos = bb * 64 + lane;
        if      (wave == 0) decode_path<1024, 400, 20, 2, 22, true,  TR>(x2, w2, b2, out, 0,  pos);
        else if (wave == 1) decode_path<1024, 400, 20, 2, 22, false, TR>(x2, w2, b2, out, 22, pos);
        else if (wave == 2) decode_path<1024, 400, 20, 2, 22, false, TR>(x2, w2, b2, out, 44, pos);
        else                decode_path<1024, 400, 20, 2, 19, false, TR>(x2, w2, b2, out, 66, pos);
    }
}

extern "C" void kernel_launch(void* const* d_in, const int* in_sizes, int n_in,
                              void* d_out, int out_size, void* d_ws, size_t ws_size,
                              hipStream_t stream)
{
    const float* x0 = (const float*)d_in[0];
    const float* x1 = (const float*)d_in[1];
    const float* x2 = (const float*)d_in[2];
    const float* W0 = (const float*)d_in[3];
    const float* b0 = (const float*)d_in[4];
    const float* W1 = (const float*)d_in[5];
    const float* b1 = (const float*)d_in[6];
    const float* W2 = (const float*)d_in[7];
    const float* b2 = (const float*)d_in[8];
    float* out = (float*)d_out;
    float* ws  = (float*)d_ws;

    const bool use_wt = ws_size >= (size_t)WS_NEED_FLOATS * sizeof(float);

    if (use_wt) {
        int prep_n = 21760 + 43520 + 87040;
        prep_wt_all<<<(prep_n + 255) / 256, 256, 0, stream>>>(W0, W1, W2, ws);
        detect_kernel<true><<<700, 256, 0, stream>>>(
            x0, x1, x2, ws + WT0_OFF, ws + WT1_OFF, ws + WT2_OFF,
            b0, b1, b2, out);
    } else {
        detect_kernel<false><<<700, 256, 0, stream>>>(
            x0, x1, x2, W0, W1, W2, b0, b1, b2, out);
    }
}

// Round 2
// 163.970 us; speedup vs baseline: 1.1747x; 1.1747x over previous
//
#include <hip/hip_runtime.h>
#include <cstdint>

// ---------------------------------------------------------------------------
// ObjectBoxDetect: 3-level YOLO head decode, fp32.
//   L0: x[16,256,80,80],  W[85,256],  stride 8,  anchors 0..6399
//   L1: x[16,512,40,40],  W[85,512],  stride 16, anchors 6400..7999
//   L2: x[16,1024,20,20], W[85,1024], stride 32, anchors 8000..8399
// out[16, 8400, 85] fp32.
//
// Round-2 structure: block = 64 spatial positions, 4 waves split the 85
// outputs {22,22,22,19} so per-thread accumulators fit in VGPRs (round-1
// had acc[85] vs VGPR_Count=52 -> scratch spill, 28% VALUBusy).
// L2 blocks first (longest serial c-chain). W transposed to Wt[c][85] and
// addressed via readfirstlane'd o_lo -> scalar s_load path.
// ---------------------------------------------------------------------------

constexpr int WT0_OFF = 0;                     // 256*85  = 21760
constexpr int WT1_OFF = 21760 + 64;            // 512*85  = 43520
constexpr int WT2_OFF = WT1_OFF + 43520 + 64;  // 1024*85 = 87040
constexpr int WS_NEED_FLOATS = WT2_OFF + 87040 + 64;

__global__ __launch_bounds__(256) void prep_wt_all(
    const float* __restrict__ W0, const float* __restrict__ W1,
    const float* __restrict__ W2, float* __restrict__ ws)
{
    int i = blockIdx.x * 256 + threadIdx.x;
    if (i < 21760) {
        int c = i / 85, o = i - 85 * c;
        ws[WT0_OFF + i] = W0[o * 256 + c];
    } else if (i < 21760 + 43520) {
        int k = i - 21760;
        int c = k / 85, o = k - 85 * c;
        ws[WT1_OFF + k] = W1[o * 512 + c];
    } else if (i < 21760 + 43520 + 87040) {
        int k = i - (21760 + 43520);
        int c = k / 85, o = k - 85 * c;
        ws[WT2_OFF + k] = W2[o * 1024 + c];
    }
}

// Decode ONUM outputs [o_lo, o_lo+ONUM) for one spatial position.
template <int C, int HW, int NXY, int LEVEL, int ONUM, bool BOX, bool TR>
__device__ __forceinline__ void decode_path(
    const float* __restrict__ feat, const float* __restrict__ Wm,
    const float* __restrict__ bias, float* __restrict__ out,
    int o_lo_in, int pos)
{
    // o_lo is wave-uniform by construction; make it provably scalar so the
    // W row reads become s_loads on the scalar pipe.
    const int o_lo = __builtin_amdgcn_readfirstlane(o_lo_in);

    const int b  = pos / HW;
    const int hw = pos - b * HW;
    const float* fp = feat + (size_t)b * (C * HW) + hw;

    float acc[ONUM];
#pragma unroll
    for (int j = 0; j < ONUM; ++j) acc[j] = bias[o_lo + j];

#pragma unroll 4
    for (int c = 0; c < C; ++c) {
        float fv = fp[(size_t)c * HW];               // coalesced across lanes
        if constexpr (TR) {
            const float* wr = Wm + c * 85 + o_lo;    // wave-uniform -> s_load
#pragma unroll
            for (int j = 0; j < ONUM; ++j)
                acc[j] = fmaf(fv, wr[j], acc[j]);
        } else {
#pragma unroll
            for (int j = 0; j < ONUM; ++j)
                acc[j] = fmaf(fv, Wm[(o_lo + j) * C + c], acc[j]);
        }
    }

    // sigmoid
#pragma unroll
    for (int j = 0; j < ONUM; ++j) {
        float e = __expf(-acc[j]);
        acc[j] = __builtin_amdgcn_rcpf(1.0f + e);
    }

    constexpr float STRIDE = (float)(8 << LEVEL);
    constexpr int AOFF = (LEVEL == 0) ? 0 : ((LEVEL == 1) ? 6400 : 8000);
    float* op = out + ((size_t)b * 8400 + AOFF + hw) * 85 + o_lo;

    if constexpr (BOX) {
        constexpr float P4 = 4.0f * (float)(1 << LEVEL);  // (2y)^2 * 2^l
        float wx = (float)(hw % NXY);
        float wy = (float)(hw / NXY);
        float d0 = acc[0] * acc[0] * P4;
        float d1 = acc[1] * acc[1] * P4;
        float d2 = acc[2] * acc[2] * P4;
        float d3 = acc[3] * acc[3] * P4;
        float x1 = (wx + 1.0f - d0) * STRIDE;
        float y1 = (wy + 1.0f - d1) * STRIDE;
        float x2 = (wx + d2) * STRIDE;
        float y2 = (wy + d3) * STRIDE;
        op[0] = (x1 + x2) * 0.5f;
        op[1] = (y1 + y2) * 0.5f;
        op[2] = x2 - x1;
        op[3] = y2 - y1;
#pragma unroll
        for (int j = 4; j < ONUM; ++j) op[j] = acc[j];
    } else {
#pragma unroll
        for (int j = 0; j < ONUM; ++j) op[j] = acc[j];
    }
}

// Per level: one block = 64 positions, 4 waves split outputs {22,22,22,19}.
// Block layout: [0,100) L2 (longest chains first), [100,500) L1, [500,2100) L0.
template <int C, int HW, int NXY, int LEVEL, bool TR>
__device__ __forceinline__ void level_block(
    const float* __restrict__ feat, const float* __restrict__ Wm,
    const float* __restrict__ bias, float* __restrict__ out, int bb)
{
    const int wave = threadIdx.x >> 6;
    const int lane = threadIdx.x & 63;
    const int pos  = bb * 64 + lane;
    if      (wave == 0) decode_path<C, HW, NXY, LEVEL, 22, true,  TR>(feat, Wm, bias, out, 0,  pos);
    else if (wave == 1) decode_path<C, HW, NXY, LEVEL, 22, false, TR>(feat, Wm, bias, out, 22, pos);
    else if (wave == 2) decode_path<C, HW, NXY, LEVEL, 22, false, TR>(feat, Wm, bias, out, 44, pos);
    else                decode_path<C, HW, NXY, LEVEL, 19, false, TR>(feat, Wm, bias, out, 66, pos);
}

template <bool TR>
__global__ __launch_bounds__(256) void detect_kernel(
    const float* __restrict__ x0, const float* __restrict__ x1,
    const float* __restrict__ x2,
    const float* __restrict__ w0, const float* __restrict__ w1,
    const float* __restrict__ w2,
    const float* __restrict__ b0, const float* __restrict__ b1,
    const float* __restrict__ b2,
    float* __restrict__ out)
{
    const int blk = blockIdx.x;
    if (blk < 100) {
        level_block<1024, 400, 20, 2, TR>(x2, w2, b2, out, blk);
    } else if (blk < 500) {
        level_block<512, 1600, 40, 1, TR>(x1, w1, b1, out, blk - 100);
    } else {
        level_block<256, 6400, 80, 0, TR>(x0, w0, b0, out, blk - 500);
    }
}

extern "C" void kernel_launch(void* const* d_in, const int* in_sizes, int n_in,
                              void* d_out, int out_size, void* d_ws, size_t ws_size,
                              hipStream_t stream)
{
    const float* x0 = (const float*)d_in[0];
    const float* x1 = (const float*)d_in[1];
    const float* x2 = (const float*)d_in[2];
    const float* W0 = (const float*)d_in[3];
    const float* b0 = (const float*)d_in[4];
    const float* W1 = (const float*)d_in[5];
    const float* b1 = (const float*)d_in[6];
    const float* W2 = (const float*)d_in[7];
    const float* b2 = (const float*)d_in[8];
    float* out = (float*)d_out;
    float* ws  = (float*)d_ws;

    const bool use_wt = ws_size >= (size_t)WS_NEED_FLOATS * sizeof(float);

    if (use_wt) {
        int prep_n = 21760 + 43520 + 87040;
        prep_wt_all<<<(prep_n + 255) / 256, 256, 0, stream>>>(W0, W1, W2, ws);
        detect_kernel<true><<<2100, 256, 0, stream>>>(
            x0, x1, x2, ws + WT0_OFF, ws + WT1_OFF, ws + WT2_OFF,
            b0, b1, b2, out);
    } else {
        detect_kernel<false><<<2100, 256, 0, stream>>>(
            x0, x1, x2, W0, W1, W2, b0, b1, b2, out);
    }
}

// Round 3
// 69.278 us; speedup vs baseline: 2.7802x; 2.3668x over previous
//
#include <hip/hip_runtime.h>
#include <cstdint>

// ---------------------------------------------------------------------------
// ObjectBoxDetect via bf16 MFMA. out[16,8400,85] fp32.
//   L0: x[16,256,80,80]  W[85,256]  stride 8   anchors [0,6400)
//   L1: x[16,512,40,40]  W[85,512]  stride 16  anchors [6400,8000)
//   L2: x[16,1024,20,20] W[85,1024] stride 32  anchors [8000,8400)
// Round-3: the contraction is a GEMM (K=256..1024) -> mfma_f32_16x16x32_bf16.
// Wave = 32 pos x 96 outs (2 M-subtiles, 6 N-tiles). A loaded direct from
// global (fp32->bf16 RNE in-register), B prepacked bf16 fragments in ws.
// No LDS, no barriers. Threshold 19.04 (bf16 floor-eps) >> bf16 error ~1.
// ---------------------------------------------------------------------------

typedef __attribute__((ext_vector_type(8))) short bf16x8;
typedef __attribute__((ext_vector_type(4))) float f32x4;

constexpr int KS0 = 8, KS1 = 16, KS2 = 32;           // K-steps per level (C/32)
constexpr int F0 = 6 * KS0, F1 = 6 * KS1, F2 = 6 * KS2;
constexpr int FOFF0 = 0, FOFF1 = F0, FOFF2 = F0 + F1;
constexpr int NFRAG = F0 + F1 + F2;                   // 336 fragments
constexpr size_t BIAS_OFF = 0;                        // 3*96 floats = 1152 B
constexpr size_t BPK_OFF  = 1152;                     // 16B aligned
constexpr size_t WS_NEED  = BPK_OFF + (size_t)NFRAG * 64 * 16;  // ~345 KB

__device__ __forceinline__ unsigned short f2bf(float f) {
    union { float f; unsigned u; } v; v.f = f;
    unsigned r = v.u + 0x7FFF + ((v.u >> 16) & 1);    // round-to-nearest-even
    return (unsigned short)(r >> 16);
}

// Pack W[o][c] (fp32) -> bf16 B-fragments, and bias -> 96-padded fp32.
// B frag layout (16x16x32): lane l holds col o = n*16+(l&15),
// k-slots c = ks*32 + (l>>4)*8 + e, e in [0,8). Same slot formula as A.
__global__ __launch_bounds__(256) void prep_pack(
    const float* __restrict__ W0, const float* __restrict__ W1,
    const float* __restrict__ W2,
    const float* __restrict__ b0, const float* __restrict__ b1,
    const float* __restrict__ b2,
    unsigned char* __restrict__ ws)
{
    int t = blockIdx.x * 256 + threadIdx.x;
    if (t < 288) {
        int lvl = t / 96, o = t % 96;
        const float* bp = (lvl == 0) ? b0 : (lvl == 1) ? b1 : b2;
        ((float*)(ws + BIAS_OFF))[t] = (o < 85) ? bp[o] : 0.0f;
    }
    if (t >= NFRAG * 64) return;
    int frag = t >> 6, l = t & 63;
    int n, ks, C; const float* W;
    if (frag < FOFF1)      { C = 256;  W = W0; int f = frag;         n = f / KS0; ks = f % KS0; }
    else if (frag < FOFF2) { C = 512;  W = W1; int f = frag - FOFF1; n = f / KS1; ks = f % KS1; }
    else                   { C = 1024; W = W2; int f = frag - FOFF2; n = f / KS2; ks = f % KS2; }
    int o  = n * 16 + (l & 15);
    int c0 = ks * 32 + (l >> 4) * 8;
    bf16x8 r;
#pragma unroll
    for (int e = 0; e < 8; ++e)
        r[e] = (o < 85) ? (short)f2bf(W[(size_t)o * C + c0 + e]) : (short)0;
    ((bf16x8*)(ws + BPK_OFF))[frag * 64 + l] = r;
}

template <int C, int HW, int NX, int LEVEL, int AOFF, int KSTEPS, int FOFF>
__device__ __forceinline__ void mfma_level(
    const float* __restrict__ feat, const unsigned char* __restrict__ ws,
    float* __restrict__ out, int blk)
{
    const int tid = threadIdx.x;
    const int w   = tid >> 6;
    const int l   = tid & 63;
    const int col = l & 15;        // N / output index within tile
    const int kg  = l >> 4;        // k-group

    // two 16-pos M-subtiles per wave; HW % 16 == 0 so each stays in one b.
    const int p0s[2] = { blk * 128 + w * 32, blk * 128 + w * 32 + 16 };
    const float* fb[2];
    int bidx[2], hw0[2];
#pragma unroll
    for (int s = 0; s < 2; ++s) {
        int b = p0s[s] / HW;
        bidx[s] = b;
        hw0[s]  = p0s[s] - b * HW;
        fb[s]   = feat + (size_t)b * C * HW + hw0[s];
    }

    const float*  bias = (const float*)(ws + BIAS_OFF) + LEVEL * 96;
    const bf16x8* bpk  = (const bf16x8*)(ws + BPK_OFF) + (size_t)FOFF * 64;

    f32x4 acc[2][6];
#pragma unroll
    for (int n = 0; n < 6; ++n) {
        float bv = bias[n * 16 + col];
        f32x4 z = { bv, bv, bv, bv };
        acc[0][n] = z;
        acc[1][n] = z;
    }

    for (int ks = 0; ks < KSTEPS; ++ks) {
        bf16x8 a[2];
#pragma unroll
        for (int s = 0; s < 2; ++s) {
            const float* p = fb[s] + col + (size_t)(ks * 32 + kg * 8) * HW;
            float f[8];
#pragma unroll
            for (int e = 0; e < 8; ++e) f[e] = p[(size_t)e * HW];
#pragma unroll
            for (int e = 0; e < 8; ++e) a[s][e] = (short)f2bf(f[e]);
        }
#pragma unroll
        for (int n = 0; n < 6; ++n) {
            bf16x8 bq = bpk[(n * KSTEPS + ks) * 64 + l];
            acc[0][n] = __builtin_amdgcn_mfma_f32_16x16x32_bf16(a[0], bq, acc[0][n], 0, 0, 0);
            acc[1][n] = __builtin_amdgcn_mfma_f32_16x16x32_bf16(a[1], bq, acc[1][n], 0, 0, 0);
        }
    }

    // Epilogue. C/D layout (m89-verified): col = l&15, row = (l>>4)*4 + j.
    constexpr float S  = (float)(8 << LEVEL);
    constexpr float P4 = 4.0f * (float)(1 << LEVEL);
#pragma unroll
    for (int s = 0; s < 2; ++s) {
        const int b = bidx[s];
#pragma unroll
        for (int j = 0; j < 4; ++j) {
            const int hw = hw0[s] + kg * 4 + j;
            float sg[6];
#pragma unroll
            for (int n = 0; n < 6; ++n) {
                float v = acc[s][n][j];
                sg[n] = __builtin_amdgcn_rcpf(1.0f + __expf(-v));
            }
            // box decode: gather sigmoid(o=0..3) for this row from lanes grp+0..3
            const int grp = l & 48;
            float y0 = __shfl(sg[0], grp + 0);
            float y1 = __shfl(sg[0], grp + 1);
            float y2 = __shfl(sg[0], grp + 2);
            float y3 = __shfl(sg[0], grp + 3);
            float wx = (float)(hw % NX);
            float wy = (float)(hw / NX);
            float d0 = y0 * y0 * P4, d1 = y1 * y1 * P4;
            float d2 = y2 * y2 * P4, d3 = y3 * y3 * P4;
            float x1 = (wx + 1.0f - d0) * S;
            float yA = (wy + 1.0f - d1) * S;
            float x2 = (wx + d2) * S;
            float yB = (wy + d3) * S;
            float bx = (x1 + x2) * 0.5f, by = (yA + yB) * 0.5f;
            float bw = x2 - x1,          bh = yB - yA;
            sg[0] = (col == 0) ? bx : (col == 1) ? by
                  : (col == 2) ? bw : (col == 3) ? bh : sg[0];
            float* op = out + ((size_t)b * 8400 + AOFF + hw) * 85;
#pragma unroll
            for (int n = 0; n < 6; ++n) {
                int o = n * 16 + col;
                if (o < 85) op[o] = sg[n];
            }
        }
    }
}

// Grid: 1050 blocks. Heaviest (L2, 32 K-steps) first.
__global__ __launch_bounds__(256, 4) void detect_mfma(
    const float* __restrict__ x0, const float* __restrict__ x1,
    const float* __restrict__ x2,
    const unsigned char* __restrict__ ws, float* __restrict__ out)
{
    int blk = blockIdx.x;
    if (blk < 50)       mfma_level<1024, 400,  20, 2, 8000, KS2, FOFF2>(x2, ws, out, blk);
    else if (blk < 250) mfma_level<512,  1600, 40, 1, 6400, KS1, FOFF1>(x1, ws, out, blk - 50);
    else                mfma_level<256,  6400, 80, 0, 0,    KS0, FOFF0>(x0, ws, out, blk - 250);
}

// ---------------- fallback (ws too small): round-2 VALU path ----------------
template <int C, int HW, int NX, int LEVEL, int ONUM, bool BOX>
__device__ __forceinline__ void decode_path_fb(
    const float* __restrict__ feat, const float* __restrict__ Wm,
    const float* __restrict__ bias, float* __restrict__ out,
    int o_lo_in, int pos)
{
    const int o_lo = __builtin_amdgcn_readfirstlane(o_lo_in);
    const int b  = pos / HW;
    const int hw = pos - b * HW;
    const float* fp = feat + (size_t)b * (C * HW) + hw;
    float acc[ONUM];
#pragma unroll
    for (int j = 0; j < ONUM; ++j) acc[j] = bias[o_lo + j];
#pragma unroll 4
    for (int c = 0; c < C; ++c) {
        float fv = fp[(size_t)c * HW];
#pragma unroll
        for (int j = 0; j < ONUM; ++j)
            acc[j] = fmaf(fv, Wm[(o_lo + j) * C + c], acc[j]);
    }
#pragma unroll
    for (int j = 0; j < ONUM; ++j)
        acc[j] = __builtin_amdgcn_rcpf(1.0f + __expf(-acc[j]));
    constexpr float S = (float)(8 << LEVEL);
    constexpr int AOFF = (LEVEL == 0) ? 0 : ((LEVEL == 1) ? 6400 : 8000);
    float* op = out + ((size_t)b * 8400 + AOFF + hw) * 85 + o_lo;
    if constexpr (BOX) {
        constexpr float P4 = 4.0f * (float)(1 << LEVEL);
        float wx = (float)(hw % NX), wy = (float)(hw / NX);
        float d0 = acc[0] * acc[0] * P4, d1 = acc[1] * acc[1] * P4;
        float d2 = acc[2] * acc[2] * P4, d3 = acc[3] * acc[3] * P4;
        float x1 = (wx + 1.0f - d0) * S, y1 = (wy + 1.0f - d1) * S;
        float x2 = (wx + d2) * S,        y2 = (wy + d3) * S;
        op[0] = (x1 + x2) * 0.5f; op[1] = (y1 + y2) * 0.5f;
        op[2] = x2 - x1;          op[3] = y2 - y1;
#pragma unroll
        for (int j = 4; j < ONUM; ++j) op[j] = acc[j];
    } else {
#pragma unroll
        for (int j = 0; j < ONUM; ++j) op[j] = acc[j];
    }
}

template <int C, int HW, int NX, int LEVEL>
__device__ __forceinline__ void level_block_fb(
    const float* __restrict__ feat, const float* __restrict__ Wm,
    const float* __restrict__ bias, float* __restrict__ out, int bb)
{
    const int wave = threadIdx.x >> 6, lane = threadIdx.x & 63;
    const int pos = bb * 64 + lane;
    if      (wave == 0) decode_path_fb<C, HW, NX, LEVEL, 22, true >(feat, Wm, bias, out, 0,  pos);
    else if (wave == 1) decode_path_fb<C, HW, NX, LEVEL, 22, false>(feat, Wm, bias, out, 22, pos);
    else if (wave == 2) decode_path_fb<C, HW, NX, LEVEL, 22, false>(feat, Wm, bias, out, 44, pos);
    else                decode_path_fb<C, HW, NX, LEVEL, 19, false>(feat, Wm, bias, out, 66, pos);
}

__global__ __launch_bounds__(256) void detect_fallback(
    const float* __restrict__ x0, const float* __restrict__ x1,
    const float* __restrict__ x2,
    const float* __restrict__ w0, const float* __restrict__ w1,
    const float* __restrict__ w2,
    const float* __restrict__ b0, const float* __restrict__ b1,
    const float* __restrict__ b2, float* __restrict__ out)
{
    const int blk = blockIdx.x;
    if (blk < 100)      level_block_fb<1024, 400,  20, 2>(x2, w2, b2, out, blk);
    else if (blk < 500) level_block_fb<512,  1600, 40, 1>(x1, w1, b1, out, blk - 100);
    else                level_block_fb<256,  6400, 80, 0>(x0, w0, b0, out, blk - 500);
}

extern "C" void kernel_launch(void* const* d_in, const int* in_sizes, int n_in,
                              void* d_out, int out_size, void* d_ws, size_t ws_size,
                              hipStream_t stream)
{
    const float* x0 = (const float*)d_in[0];
    const float* x1 = (const float*)d_in[1];
    const float* x2 = (const float*)d_in[2];
    const float* W0 = (const float*)d_in[3];
    const float* b0 = (const float*)d_in[4];
    const float* W1 = (const float*)d_in[5];
    const float* b1 = (const float*)d_in[6];
    const float* W2 = (const float*)d_in[7];
    const float* b2 = (const float*)d_in[8];
    float* out = (float*)d_out;

    if (ws_size >= WS_NEED) {
        unsigned char* ws = (unsigned char*)d_ws;
        prep_pack<<<(NFRAG * 64 + 255) / 256, 256, 0, stream>>>(W0, W1, W2, b0, b1, b2, ws);
        detect_mfma<<<1050, 256, 0, stream>>>(x0, x1, x2, ws, out);
    } else {
        detect_fallback<<<2100, 256, 0, stream>>>(x0, x1, x2, W0, W1, W2, b0, b1, b2, out);
    }
}

// Round 5
// 52.568 us; speedup vs baseline: 3.6640x; 1.3179x over previous
//
#include <hip/hip_runtime.h>
#include <cstdint>

// ---------------------------------------------------------------------------
// ObjectBoxDetect via bf16 MFMA. out[16,8400,85] fp32.
//   L0: x[16,256,80,80]  W[85,256]  stride 8   anchors [0,6400)
//   L1: x[16,512,40,40]  W[85,512]  stride 16  anchors [6400,8000)
//   L2: x[16,1024,20,20] W[85,1024] stride 32  anchors [8000,8400)
//
// Round-5: round-4's LDS B-staging was right (B L2-traffic 268->67 MB) but
// shared one batch index per 32-pos wave; L2 has HW=400 (not /32) so waves
// straddled batch boundaries -> absmax 882. Restore round-3's PER-16-SUBTILE
// b/hw0 (HW%16==0 for all levels), keep the double-buffered LDS B pipeline.
// ---------------------------------------------------------------------------

typedef __attribute__((ext_vector_type(8))) short bf16x8;
typedef __attribute__((ext_vector_type(4))) float f32x4;

constexpr int KS0 = 8, KS1 = 16, KS2 = 32;            // K-steps per level (C/32)
constexpr int F0 = 6 * KS0, F1 = 6 * KS1, F2 = 6 * KS2;
constexpr int FOFF0 = 0, FOFF1 = F0, FOFF2 = F0 + F1;
constexpr int NFRAG = F0 + F1 + F2;                    // 336 fragments
constexpr size_t BIAS_OFF = 0;                         // 3*96 floats = 1152 B
constexpr size_t BPK_OFF  = 1152;                      // 16B aligned
constexpr size_t WS_NEED  = BPK_OFF + (size_t)NFRAG * 64 * 16;

__device__ __forceinline__ unsigned short f2bf(float f) {
    union { float f; unsigned u; } v; v.f = f;
    unsigned r = v.u + 0x7FFF + ((v.u >> 16) & 1);     // round-to-nearest-even
    return (unsigned short)(r >> 16);
}

// Pack W[o][c] -> bf16 B-fragments ([ks][n]-major per level) + padded bias.
// B frag layout (16x16x32): lane l holds col o = n*16+(l&15),
// k-slots c = ks*32 + (l>>4)*8 + e.
__global__ __launch_bounds__(256) void prep_pack(
    const float* __restrict__ W0, const float* __restrict__ W1,
    const float* __restrict__ W2,
    const float* __restrict__ b0, const float* __restrict__ b1,
    const float* __restrict__ b2,
    unsigned char* __restrict__ ws)
{
    int t = blockIdx.x * 256 + threadIdx.x;
    if (t < 288) {
        int lvl = t / 96, o = t % 96;
        const float* bp = (lvl == 0) ? b0 : (lvl == 1) ? b1 : b2;
        ((float*)(ws + BIAS_OFF))[t] = (o < 85) ? bp[o] : 0.0f;
    }
    if (t >= NFRAG * 64) return;
    int frag = t >> 6, l = t & 63;
    int C; const float* W; int f;
    if (frag < FOFF1)      { C = 256;  W = W0; f = frag;         }
    else if (frag < FOFF2) { C = 512;  W = W1; f = frag - FOFF1; }
    else                   { C = 1024; W = W2; f = frag - FOFF2; }
    int ks = f / 6, n = f % 6;                          // [ks][n]-major
    int o  = n * 16 + (l & 15);
    int c0 = ks * 32 + (l >> 4) * 8;
    bf16x8 r;
#pragma unroll
    for (int e = 0; e < 8; ++e)
        r[e] = (o < 85) ? (short)f2bf(W[(size_t)o * C + c0 + e]) : (short)0;
    ((bf16x8*)(ws + BPK_OFF))[frag * 64 + l] = r;
}

template <int C, int HW, int NX, int LEVEL, int AOFF, int KSTEPS, int FOFF>
__device__ __forceinline__ void mfma_level(
    const float* __restrict__ feat, const unsigned char* __restrict__ ws,
    float* __restrict__ out, int blk, uint4* __restrict__ Bsm /* [2][384] */)
{
    const int tid = threadIdx.x;
    const int w   = tid >> 6;
    const int l   = tid & 63;
    const int col = l & 15;            // output col within 16-tile
    const int kg  = l >> 4;            // k-group

    // two 16-pos M-subtiles per wave; HW % 16 == 0 so each stays in one batch.
    const int p0s[2] = { blk * 128 + w * 32, blk * 128 + w * 32 + 16 };
    const float* fb[2];
    int bidx[2], hw0[2];
#pragma unroll
    for (int s = 0; s < 2; ++s) {
        int b   = p0s[s] / HW;
        bidx[s] = b;
        hw0[s]  = p0s[s] - b * HW;
        fb[s]   = feat + (size_t)b * C * HW + hw0[s];
    }

    const float* bias = (const float*)(ws + BIAS_OFF) + LEVEL * 96;
    const uint4* bsrc = (const uint4*)(ws + BPK_OFF) + (size_t)FOFF * 64;

    f32x4 acc[2][6];
#pragma unroll
    for (int n = 0; n < 6; ++n) {
        float bv = bias[n * 16 + col];
        f32x4 z = { bv, bv, bv, bv };
        acc[0][n] = z;
        acc[1][n] = z;
    }

    // prologue: stage B(ks=0) into buffer 0
    {
        const uint4* s = bsrc;                   // ks=0: 384 uint4 = 6KB
        Bsm[tid] = s[tid];
        if (tid < 128) Bsm[256 + tid] = s[256 + tid];
    }
    __syncthreads();

    int cur = 0;
    for (int ks = 0; ks < KSTEPS; ++ks) {
        // ---- A loads (direct global, coalesced 64B segments) ----
        float fl0[8], fl1[8];
        const float* p0p = fb[0] + col + (size_t)(ks * 32 + kg * 8) * HW;
        const float* p1p = fb[1] + col + (size_t)(ks * 32 + kg * 8) * HW;
#pragma unroll
        for (int e = 0; e < 8; ++e) fl0[e] = p0p[(size_t)e * HW];
#pragma unroll
        for (int e = 0; e < 8; ++e) fl1[e] = p1p[(size_t)e * HW];

        // ---- issue next k-step's B stage loads (in flight during compute) --
        uint4 s0, s1;
        const int ksn = (ks + 1 < KSTEPS) ? ks + 1 : ks;
        {
            const uint4* s = bsrc + (size_t)ksn * 384;
            s0 = s[tid];
            if (tid < 128) s1 = s[256 + tid];
        }

        // ---- cvt fp32 -> bf16 fragments ----
        bf16x8 a0, a1;
#pragma unroll
        for (int e = 0; e < 8; ++e) a0[e] = (short)f2bf(fl0[e]);
#pragma unroll
        for (int e = 0; e < 8; ++e) a1[e] = (short)f2bf(fl1[e]);

        // ---- B from LDS (shared by all 4 waves) + MFMA ----
        const bf16x8* bl = (const bf16x8*)(Bsm + (size_t)cur * 384);
#pragma unroll
        for (int n = 0; n < 6; ++n) {
            bf16x8 bq = bl[n * 64 + l];
            acc[0][n] = __builtin_amdgcn_mfma_f32_16x16x32_bf16(a0, bq, acc[0][n], 0, 0, 0);
            acc[1][n] = __builtin_amdgcn_mfma_f32_16x16x32_bf16(a1, bq, acc[1][n], 0, 0, 0);
        }

        // ---- write staged B to the other buffer, flip ----
        if (ks + 1 < KSTEPS) {
            uint4* d = Bsm + (size_t)(cur ^ 1) * 384;
            d[tid] = s0;
            if (tid < 128) d[256 + tid] = s1;
        }
        __syncthreads();
        cur ^= 1;
    }

    // Epilogue. C/D layout (m89-verified): col = l&15, row = (l>>4)*4 + j.
    constexpr float S  = (float)(8 << LEVEL);
    constexpr float P4 = 4.0f * (float)(1 << LEVEL);
#pragma unroll
    for (int s = 0; s < 2; ++s) {
        const int b = bidx[s];
#pragma unroll
        for (int j = 0; j < 4; ++j) {
            const int hw = hw0[s] + kg * 4 + j;
            float sg[6];
#pragma unroll
            for (int n = 0; n < 6; ++n) {
                float v = acc[s][n][j];
                sg[n] = __builtin_amdgcn_rcpf(1.0f + __expf(-v));
            }
            const int grp = l & 48;
            float y0 = __shfl(sg[0], grp + 0);
            float y1 = __shfl(sg[0], grp + 1);
            float y2 = __shfl(sg[0], grp + 2);
            float y3 = __shfl(sg[0], grp + 3);
            float wx = (float)(hw % NX);
            float wy = (float)(hw / NX);
            float d0 = y0 * y0 * P4, d1 = y1 * y1 * P4;
            float d2 = y2 * y2 * P4, d3 = y3 * y3 * P4;
            float x1 = (wx + 1.0f - d0) * S;
            float yA = (wy + 1.0f - d1) * S;
            float x2 = (wx + d2) * S;
            float yB = (wy + d3) * S;
            float bx = (x1 + x2) * 0.5f, by = (yA + yB) * 0.5f;
            float bw = x2 - x1,          bh = yB - yA;
            sg[0] = (col == 0) ? bx : (col == 1) ? by
                  : (col == 2) ? bw : (col == 3) ? bh : sg[0];
            float* op = out + ((size_t)b * 8400 + AOFF + hw) * 85;
#pragma unroll
            for (int n = 0; n < 6; ++n) {
                int o = n * 16 + col;
                if (o < 85) op[o] = sg[n];
            }
        }
    }
}

// Grid: 1050 blocks of 128 positions. Heaviest (L2, 32 barriered k-steps) first.
__global__ __launch_bounds__(256, 4) void detect_mfma(
    const float* __restrict__ x0, const float* __restrict__ x1,
    const float* __restrict__ x2,
    const unsigned char* __restrict__ ws, float* __restrict__ out)
{
    __shared__ uint4 Bsm[2 * 384];     // 12 KB double-buffered B stage
    int blk = blockIdx.x;
    if (blk < 50)       mfma_level<1024, 400,  20, 2, 8000, KS2, FOFF2>(x2, ws, out, blk,       Bsm);
    else if (blk < 250) mfma_level<512,  1600, 40, 1, 6400, KS1, FOFF1>(x1, ws, out, blk - 50,  Bsm);
    else                mfma_level<256,  6400, 80, 0, 0,    KS0, FOFF0>(x0, ws, out, blk - 250, Bsm);
}

// ---------------- fallback (ws too small): round-2 VALU path ----------------
template <int C, int HW, int NX, int LEVEL, int ONUM, bool BOX>
__device__ __forceinline__ void decode_path_fb(
    const float* __restrict__ feat, const float* __restrict__ Wm,
    const float* __restrict__ bias, float* __restrict__ out,
    int o_lo_in, int pos)
{
    const int o_lo = __builtin_amdgcn_readfirstlane(o_lo_in);
    const int b  = pos / HW;
    const int hw = pos - b * HW;
    const float* fp = feat + (size_t)b * (C * HW) + hw;
    float acc[ONUM];
#pragma unroll
    for (int j = 0; j < ONUM; ++j) acc[j] = bias[o_lo + j];
#pragma unroll 4
    for (int c = 0; c < C; ++c) {
        float fv = fp[(size_t)c * HW];
#pragma unroll
        for (int j = 0; j < ONUM; ++j)
            acc[j] = fmaf(fv, Wm[(o_lo + j) * C + c], acc[j]);
    }
#pragma unroll
    for (int j = 0; j < ONUM; ++j)
        acc[j] = __builtin_amdgcn_rcpf(1.0f + __expf(-acc[j]));
    constexpr float S = (float)(8 << LEVEL);
    constexpr int AOFF = (LEVEL == 0) ? 0 : ((LEVEL == 1) ? 6400 : 8000);
    float* op = out + ((size_t)b * 8400 + AOFF + hw) * 85 + o_lo;
    if constexpr (BOX) {
        constexpr float P4 = 4.0f * (float)(1 << LEVEL);
        float wx = (float)(hw % NX), wy = (float)(hw / NX);
        float d0 = acc[0] * acc[0] * P4, d1 = acc[1] * acc[1] * P4;
        float d2 = acc[2] * acc[2] * P4, d3 = acc[3] * acc[3] * P4;
        float x1 = (wx + 1.0f - d0) * S, y1 = (wy + 1.0f - d1) * S;
        float x2 = (wx + d2) * S,        y2 = (wy + d3) * S;
        op[0] = (x1 + x2) * 0.5f; op[1] = (y1 + y2) * 0.5f;
        op[2] = x2 - x1;          op[3] = y2 - y1;
#pragma unroll
        for (int j = 4; j < ONUM; ++j) op[j] = acc[j];
    } else {
#pragma unroll
        for (int j = 0; j < ONUM; ++j) op[j] = acc[j];
    }
}

template <int C, int HW, int NX, int LEVEL>
__device__ __forceinline__ void level_block_fb(
    const float* __restrict__ feat, const float* __restrict__ Wm,
    const float* __restrict__ bias, float* __restrict__ out, int bb)
{
    const int wave = threadIdx.x >> 6, lane = threadIdx.x & 63;
    const int pos = bb * 64 + lane;
    if      (wave == 0) decode_path_fb<C, HW, NX, LEVEL, 22, true >(feat, Wm, bias, out, 0,  pos);
    else if (wave == 1) decode_path_fb<C, HW, NX, LEVEL, 22, false>(feat, Wm, bias, out, 22, pos);
    else if (wave == 2) decode_path_fb<C, HW, NX, LEVEL, 22, false>(feat, Wm, bias, out, 44, pos);
    else                decode_path_fb<C, HW, NX, LEVEL, 19, false>(feat, Wm, bias, out, 66, pos);
}

__global__ __launch_bounds__(256) void detect_fallback(
    const float* __restrict__ x0, const float* __restrict__ x1,
    const float* __restrict__ x2,
    const float* __restrict__ w0, const float* __restrict__ w1,
    const float* __restrict__ w2,
    const float* __restrict__ b0, const float* __restrict__ b1,
    const float* __restrict__ b2, float* __restrict__ out)
{
    const int blk = blockIdx.x;
    if (blk < 100)      level_block_fb<1024, 400,  20, 2>(x2, w2, b2, out, blk);
    else if (blk < 500) level_block_fb<512,  1600, 40, 1>(x1, w1, b1, out, blk - 100);
    else                level_block_fb<256,  6400, 80, 0>(x0, w0, b0, out, blk - 500);
}

extern "C" void kernel_launch(void* const* d_in, const int* in_sizes, int n_in,
                              void* d_out, int out_size, void* d_ws, size_t ws_size,
                              hipStream_t stream)
{
    const float* x0 = (const float*)d_in[0];
    const float* x1 = (const float*)d_in[1];
    const float* x2 = (const float*)d_in[2];
    const float* W0 = (const float*)d_in[3];
    const float* b0 = (const float*)d_in[4];
    const float* W1 = (const float*)d_in[5];
    const float* b1 = (const float*)d_in[6];
    const float* W2 = (const float*)d_in[7];
    const float* b2 = (const float*)d_in[8];
    float* out = (float*)d_out;

    if (ws_size >= WS_NEED) {
        unsigned char* ws = (unsigned char*)d_ws;
        prep_pack<<<(NFRAG * 64 + 255) / 256, 256, 0, stream>>>(W0, W1, W2, b0, b1, b2, ws);
        detect_mfma<<<1050, 256, 0, stream>>>(x0, x1, x2, ws, out);
    } else {
        detect_fallback<<<2100, 256, 0, stream>>>(x0, x1, x2, W0, W1, W2, b0, b1, b2, out);
    }
}

// Round 6
// 47.904 us; speedup vs baseline: 4.0208x; 1.0974x over previous
//
#include <hip/hip_runtime.h>
#include <cstdint>

// ---------------------------------------------------------------------------
// ObjectBoxDetect via bf16 MFMA. out[16,8400,85] fp32.
//   L0: x[16,256,80,80]  W[85,256]  stride 8   anchors [0,6400)
//   L1: x[16,512,40,40]  W[85,512]  stride 16  anchors [6400,8000)
//   L2: x[16,1024,20,20] W[85,1024] stride 32  anchors [8000,8400)
//
// Round-6: round-5 was latency-bound (VALUBusy 11%, MfmaUtil 3.5%, HBM 19%):
// grid-capped occupancy (4200 waves / 8192 slots) + serial A-load->cvt->MFMA
// chain exposed ~900cy HBM latency per barriered k-step. Now:
//   * M=16 per wave (1 subtile, 6 MFMA/kstep) -> 8400 waves (2100 blocks).
//   * A(ks+1) prefetched into regs BEFORE MFMA(ks) -> latency hides under
//     compute + barrier (B reg->LDS double-buffer prefetch kept from r5).
// ---------------------------------------------------------------------------

typedef __attribute__((ext_vector_type(8))) short bf16x8;
typedef __attribute__((ext_vector_type(4))) float f32x4;

constexpr int KS0 = 8, KS1 = 16, KS2 = 32;            // K-steps per level (C/32)
constexpr int F0 = 6 * KS0, F1 = 6 * KS1, F2 = 6 * KS2;
constexpr int FOFF0 = 0, FOFF1 = F0, FOFF2 = F0 + F1;
constexpr int NFRAG = F0 + F1 + F2;                    // 336 fragments
constexpr size_t BIAS_OFF = 0;                         // 3*96 floats = 1152 B
constexpr size_t BPK_OFF  = 1152;                      // 16B aligned
constexpr size_t WS_NEED  = BPK_OFF + (size_t)NFRAG * 64 * 16;

__device__ __forceinline__ unsigned short f2bf(float f) {
    union { float f; unsigned u; } v; v.f = f;
    unsigned r = v.u + 0x7FFF + ((v.u >> 16) & 1);     // round-to-nearest-even
    return (unsigned short)(r >> 16);
}

// Pack W[o][c] -> bf16 B-fragments ([ks][n]-major per level) + padded bias.
// B frag layout (16x16x32): lane l holds col o = n*16+(l&15),
// k-slots c = ks*32 + (l>>4)*8 + e.
__global__ __launch_bounds__(256) void prep_pack(
    const float* __restrict__ W0, const float* __restrict__ W1,
    const float* __restrict__ W2,
    const float* __restrict__ b0, const float* __restrict__ b1,
    const float* __restrict__ b2,
    unsigned char* __restrict__ ws)
{
    int t = blockIdx.x * 256 + threadIdx.x;
    if (t < 288) {
        int lvl = t / 96, o = t % 96;
        const float* bp = (lvl == 0) ? b0 : (lvl == 1) ? b1 : b2;
        ((float*)(ws + BIAS_OFF))[t] = (o < 85) ? bp[o] : 0.0f;
    }
    if (t >= NFRAG * 64) return;
    int frag = t >> 6, l = t & 63;
    int C; const float* W; int f;
    if (frag < FOFF1)      { C = 256;  W = W0; f = frag;         }
    else if (frag < FOFF2) { C = 512;  W = W1; f = frag - FOFF1; }
    else                   { C = 1024; W = W2; f = frag - FOFF2; }
    int ks = f / 6, n = f % 6;                          // [ks][n]-major
    int o  = n * 16 + (l & 15);
    int c0 = ks * 32 + (l >> 4) * 8;
    bf16x8 r;
#pragma unroll
    for (int e = 0; e < 8; ++e)
        r[e] = (o < 85) ? (short)f2bf(W[(size_t)o * C + c0 + e]) : (short)0;
    ((bf16x8*)(ws + BPK_OFF))[frag * 64 + l] = r;
}

template <int C, int HW, int NX, int LEVEL, int AOFF, int KSTEPS, int FOFF>
__device__ __forceinline__ void mfma_level(
    const float* __restrict__ feat, const unsigned char* __restrict__ ws,
    float* __restrict__ out, int blk, uint4* __restrict__ Bsm /* [2][384] */)
{
    const int tid = threadIdx.x;
    const int w   = tid >> 6;
    const int l   = tid & 63;
    const int col = l & 15;            // output col within 16-tile
    const int kg  = l >> 4;            // k-group

    // one 16-pos M-subtile per wave; HW % 16 == 0 so it stays in one batch.
    const int p0  = blk * 64 + w * 16;
    const int b   = p0 / HW;
    const int hw0 = p0 - b * HW;
    const float* fb = feat + (size_t)b * C * HW + hw0;

    const float* bias = (const float*)(ws + BIAS_OFF) + LEVEL * 96;
    const uint4* bsrc = (const uint4*)(ws + BPK_OFF) + (size_t)FOFF * 64;

    f32x4 acc[6];
#pragma unroll
    for (int n = 0; n < 6; ++n) {
        float bv = bias[n * 16 + col];
        f32x4 z = { bv, bv, bv, bv };
        acc[n] = z;
    }

    // prologue: stage B(ks=0) into buffer 0; load A(ks=0) into regs
    {
        const uint4* s = bsrc;                   // ks=0: 384 uint4 = 6KB
        Bsm[tid] = s[tid];
        if (tid < 128) Bsm[256 + tid] = s[256 + tid];
    }
    float fl_cur[8];
    {
        const float* p = fb + col + (size_t)(kg * 8) * HW;
#pragma unroll
        for (int e = 0; e < 8; ++e) fl_cur[e] = p[(size_t)e * HW];
    }
    __syncthreads();

    int cur = 0;
    for (int ks = 0; ks < KSTEPS; ++ks) {
        // ---- prefetch A(ks+1) (HBM, hides under MFMA + barrier) ----
        float fl_next[8];
        if (ks + 1 < KSTEPS) {
            const float* p = fb + col + (size_t)((ks + 1) * 32 + kg * 8) * HW;
#pragma unroll
            for (int e = 0; e < 8; ++e) fl_next[e] = p[(size_t)e * HW];
        }

        // ---- prefetch B(ks+1) stage loads into regs ----
        uint4 s0, s1;
        if (ks + 1 < KSTEPS) {
            const uint4* s = bsrc + (size_t)(ks + 1) * 384;
            s0 = s[tid];
            if (tid < 128) s1 = s[256 + tid];
        }

        // ---- cvt fp32 -> bf16 fragment (A(ks) loaded last iteration) ----
        bf16x8 a;
#pragma unroll
        for (int e = 0; e < 8; ++e) a[e] = (short)f2bf(fl_cur[e]);

        // ---- B from LDS (shared by all 4 waves) + MFMA ----
        const bf16x8* bl = (const bf16x8*)(Bsm + (size_t)cur * 384);
#pragma unroll
        for (int n = 0; n < 6; ++n) {
            bf16x8 bq = bl[n * 64 + l];
            acc[n] = __builtin_amdgcn_mfma_f32_16x16x32_bf16(a, bq, acc[n], 0, 0, 0);
        }

        // ---- write staged B to the other buffer, flip ----
        if (ks + 1 < KSTEPS) {
            uint4* d = Bsm + (size_t)(cur ^ 1) * 384;
            d[tid] = s0;
            if (tid < 128) d[256 + tid] = s1;
#pragma unroll
            for (int e = 0; e < 8; ++e) fl_cur[e] = fl_next[e];
        }
        __syncthreads();
        cur ^= 1;
    }

    // Epilogue. C/D layout (m89-verified): col = l&15, row = (l>>4)*4 + j.
    constexpr float S  = (float)(8 << LEVEL);
    constexpr float P4 = 4.0f * (float)(1 << LEVEL);
#pragma unroll
    for (int j = 0; j < 4; ++j) {
        const int hw = hw0 + kg * 4 + j;
        float sg[6];
#pragma unroll
        for (int n = 0; n < 6; ++n) {
            float v = acc[n][j];
            sg[n] = __builtin_amdgcn_rcpf(1.0f + __expf(-v));
        }
        const int grp = l & 48;
        float y0 = __shfl(sg[0], grp + 0);
        float y1 = __shfl(sg[0], grp + 1);
        float y2 = __shfl(sg[0], grp + 2);
        float y3 = __shfl(sg[0], grp + 3);
        float wx = (float)(hw % NX);
        float wy = (float)(hw / NX);
        float d0 = y0 * y0 * P4, d1 = y1 * y1 * P4;
        float d2 = y2 * y2 * P4, d3 = y3 * y3 * P4;
        float x1 = (wx + 1.0f - d0) * S;
        float yA = (wy + 1.0f - d1) * S;
        float x2 = (wx + d2) * S;
        float yB = (wy + d3) * S;
        float bx = (x1 + x2) * 0.5f, by = (yA + yB) * 0.5f;
        float bw = x2 - x1,          bh = yB - yA;
        sg[0] = (col == 0) ? bx : (col == 1) ? by
              : (col == 2) ? bw : (col == 3) ? bh : sg[0];
        float* op = out + ((size_t)b * 8400 + AOFF + hw) * 85;
#pragma unroll
        for (int n = 0; n < 6; ++n) {
            int o = n * 16 + col;
            if (o < 85) op[o] = sg[n];
        }
    }
}

// Grid: 2100 blocks of 64 positions. Heaviest (L2, 32 barriered k-steps) first.
__global__ __launch_bounds__(256, 6) void detect_mfma(
    const float* __restrict__ x0, const float* __restrict__ x1,
    const float* __restrict__ x2,
    const unsigned char* __restrict__ ws, float* __restrict__ out)
{
    __shared__ uint4 Bsm[2 * 384];     // 12 KB double-buffered B stage
    int blk = blockIdx.x;
    if (blk < 100)      mfma_level<1024, 400,  20, 2, 8000, KS2, FOFF2>(x2, ws, out, blk,       Bsm);
    else if (blk < 500) mfma_level<512,  1600, 40, 1, 6400, KS1, FOFF1>(x1, ws, out, blk - 100, Bsm);
    else                mfma_level<256,  6400, 80, 0, 0,    KS0, FOFF0>(x0, ws, out, blk - 500, Bsm);
}

// ---------------- fallback (ws too small): round-2 VALU path ----------------
template <int C, int HW, int NX, int LEVEL, int ONUM, bool BOX>
__device__ __forceinline__ void decode_path_fb(
    const float* __restrict__ feat, const float* __restrict__ Wm,
    const float* __restrict__ bias, float* __restrict__ out,
    int o_lo_in, int pos)
{
    const int o_lo = __builtin_amdgcn_readfirstlane(o_lo_in);
    const int b  = pos / HW;
    const int hw = pos - b * HW;
    const float* fp = feat + (size_t)b * (C * HW) + hw;
    float acc[ONUM];
#pragma unroll
    for (int j = 0; j < ONUM; ++j) acc[j] = bias[o_lo + j];
#pragma unroll 4
    for (int c = 0; c < C; ++c) {
        float fv = fp[(size_t)c * HW];
#pragma unroll
        for (int j = 0; j < ONUM; ++j)
            acc[j] = fmaf(fv, Wm[(o_lo + j) * C + c], acc[j]);
    }
#pragma unroll
    for (int j = 0; j < ONUM; ++j)
        acc[j] = __builtin_amdgcn_rcpf(1.0f + __expf(-acc[j]));
    constexpr float S = (float)(8 << LEVEL);
    constexpr int AOFF = (LEVEL == 0) ? 0 : ((LEVEL == 1) ? 6400 : 8000);
    float* op = out + ((size_t)b * 8400 + AOFF + hw) * 85 + o_lo;
    if constexpr (BOX) {
        constexpr float P4 = 4.0f * (float)(1 << LEVEL);
        float wx = (float)(hw % NX), wy = (float)(hw / NX);
        float d0 = acc[0] * acc[0] * P4, d1 = acc[1] * acc[1] * P4;
        float d2 = acc[2] * acc[2] * P4, d3 = acc[3] * acc[3] * P4;
        float x1 = (wx + 1.0f - d0) * S, y1 = (wy + 1.0f - d1) * S;
        float x2 = (wx + d2) * S,        y2 = (wy + d3) * S;
        op[0] = (x1 + x2) * 0.5f; op[1] = (y1 + y2) * 0.5f;
        op[2] = x2 - x1;          op[3] = y2 - y1;
#pragma unroll
        for (int j = 4; j < ONUM; ++j) op[j] = acc[j];
    } else {
#pragma unroll
        for (int j = 0; j < ONUM; ++j) op[j] = acc[j];
    }
}

template <int C, int HW, int NX, int LEVEL>
__device__ __forceinline__ void level_block_fb(
    const float* __restrict__ feat, const float* __restrict__ Wm,
    const float* __restrict__ bias, float* __restrict__ out, int bb)
{
    const int wave = threadIdx.x >> 6, lane = threadIdx.x & 63;
    const int pos = bb * 64 + lane;
    if      (wave == 0) decode_path_fb<C, HW, NX, LEVEL, 22, true >(feat, Wm, bias, out, 0,  pos);
    else if (wave == 1) decode_path_fb<C, HW, NX, LEVEL, 22, false>(feat, Wm, bias, out, 22, pos);
    else if (wave == 2) decode_path_fb<C, HW, NX, LEVEL, 22, false>(feat, Wm, bias, out, 44, pos);
    else                decode_path_fb<C, HW, NX, LEVEL, 19, false>(feat, Wm, bias, out, 66, pos);
}

__global__ __launch_bounds__(256) void detect_fallback(
    const float* __restrict__ x0, const float* __restrict__ x1,
    const float* __restrict__ x2,
    const float* __restrict__ w0, const float* __restrict__ w1,
    const float* __restrict__ w2,
    const float* __restrict__ b0, const float* __restrict__ b1,
    const float* __restrict__ b2, float* __restrict__ out)
{
    const int blk = blockIdx.x;
    if (blk < 100)      level_block_fb<1024, 400,  20, 2>(x2, w2, b2, out, blk);
    else if (blk < 500) level_block_fb<512,  1600, 40, 1>(x1, w1, b1, out, blk - 100);
    else                level_block_fb<256,  6400, 80, 0>(x0, w0, b0, out, blk - 500);
}

extern "C" void kernel_launch(void* const* d_in, const int* in_sizes, int n_in,
                              void* d_out, int out_size, void* d_ws, size_t ws_size,
                              hipStream_t stream)
{
    const float* x0 = (const float*)d_in[0];
    const float* x1 = (const float*)d_in[1];
    const float* x2 = (const float*)d_in[2];
    const float* W0 = (const float*)d_in[3];
    const float* b0 = (const float*)d_in[4];
    const float* W1 = (const float*)d_in[5];
    const float* b1 = (const float*)d_in[6];
    const float* W2 = (const float*)d_in[7];
    const float* b2 = (const float*)d_in[8];
    float* out = (float*)d_out;

    if (ws_size >= WS_NEED) {
        unsigned char* ws = (unsigned char*)d_ws;
        prep_pack<<<(NFRAG * 64 + 255) / 256, 256, 0, stream>>>(W0, W1, W2, b0, b1, b2, ws);
        detect_mfma<<<2100, 256, 0, stream>>>(x0, x1, x2, ws, out);
    } else {
        detect_fallback<<<2100, 256, 0, stream>>>(x0, x1, x2, W0, W1, W2, b0, b1, b2, out);
    }
}